// Round 1
// baseline (663.937 us; speedup 1.0000x reference)
//
#include <hip/hip_runtime.h>
#include <cmath>

// LabelSmoothKLDivLoss — closed form:
// loss = C + (1/N) * sum_i [ lse_i - PB*rowsum_i - (1-eps-PB)*x[i,y_i] ]
// C = eps*log(PB) + (1-eps)*log(1-eps)   (host, double precision)
//
// Single pass over x (524 MB) => memory-bound, floor ~90 us @ 6.3 TB/s.
// R0 (this session): plain cached vector loads (NT hint removed — only
// deviation from the known-good 6.29 TB/s float4-copy recipe),
// __launch_bounds__(256,8) to pin 8 waves/SIMD, explicit exp2-domain
// fma+v_exp_f32 per element, and x[row,y] load hoisted to kernel entry
// so its HBM latency overlaps the streaming loop.

#define NCLASS 32000
#define NROWS  4096
#define NVEC   (NCLASS / 4)   // 8000 float4 per row

constexpr float EPSILON_F = 0.1f;
constexpr float PB_F      = 0.1f / 31999.0f;
constexpr float LOG2E_F   = 1.44269504088896340736f;
constexpr float SHIFT2_F  = 16.0f * 1.44269504088896340736f;  // shift in exp2 domain
constexpr float LN2_F     = 0.69314718055994530942f;

typedef float vf4 __attribute__((ext_vector_type(4)));

__device__ __forceinline__ void acc_update(vf4 v, float& s, float& rs) {
    // e = exp(x - 16) computed as exp2(x*log2e - 16*log2e): 1 fma + 1 v_exp_f32
    float e0 = __builtin_amdgcn_exp2f(__builtin_fmaf(v.x, LOG2E_F, -SHIFT2_F));
    float e1 = __builtin_amdgcn_exp2f(__builtin_fmaf(v.y, LOG2E_F, -SHIFT2_F));
    float e2 = __builtin_amdgcn_exp2f(__builtin_fmaf(v.z, LOG2E_F, -SHIFT2_F));
    float e3 = __builtin_amdgcn_exp2f(__builtin_fmaf(v.w, LOG2E_F, -SHIFT2_F));
    s  += (e0 + e1) + (e2 + e3);
    rs += (v.x + v.y) + (v.z + v.w);
}

__global__ __launch_bounds__(256, 8)
void ls_kldiv_row_kernel(const float* __restrict__ x,
                         const int*   __restrict__ y,
                         float*       __restrict__ partial) {
    const int row = blockIdx.x;
    const int tid = threadIdx.x;
    const vf4* __restrict__ xr =
        reinterpret_cast<const vf4*>(x + (size_t)row * NCLASS);

    // Hoist the target-class load: issue it before the streaming loop so
    // its latency overlaps ~8000 cycles of main-loop work.
    float xy = 0.f;
    if (tid == 0) {
        xy = x[(size_t)row * NCLASS + y[row]];
    }

    float s0 = 0.f, s1 = 0.f, s2 = 0.f, s3 = 0.f;
    float r0 = 0.f, r1 = 0.f, r2 = 0.f, r3 = 0.f;

    int base = tid;
    // full 4-wide chunks: all four loads in-bounds
    for (; base + 768 < NVEC; base += 1024) {
        vf4 v0 = xr[base];
        vf4 v1 = xr[base + 256];
        vf4 v2 = xr[base + 512];
        vf4 v3 = xr[base + 768];
        acc_update(v0, s0, r0);
        acc_update(v1, s1, r1);
        acc_update(v2, s2, r2);
        acc_update(v3, s3, r3);
    }
    // tail: single-stream
    for (; base < NVEC; base += 256) {
        vf4 v = xr[base];
        acc_update(v, s0, r0);
    }

    float s  = (s0 + s1) + (s2 + s3);
    float rs = (r0 + r1) + (r2 + r3);

    // wave (64-lane) butterfly reduction
    #pragma unroll
    for (int off = 1; off < 64; off <<= 1) {
        s  += __shfl_xor(s,  off);
        rs += __shfl_xor(rs, off);
    }

    // cross-wave reduction (4 waves per block)
    __shared__ float ss[4], srs[4];
    const int wave = tid >> 6;
    const int lane = tid & 63;
    if (lane == 0) { ss[wave] = s; srs[wave] = rs; }
    __syncthreads();

    if (tid == 0) {
        s  = (ss[0]  + ss[1])  + (ss[2]  + ss[3]);
        rs = (srs[0] + srs[1]) + (srs[2] + srs[3]);
        // lse = 16 + ln(sum exp(x-16)) == LN2 * (SHIFT2 + log2(s))
        float lse = LN2_F * (SHIFT2_F + __builtin_amdgcn_logf(s));
        partial[row] = lse - PB_F * rs - (1.0f - EPSILON_F - PB_F) * xy;
    }
}

__global__ __launch_bounds__(256)
void ls_kldiv_reduce_kernel(const float* __restrict__ partial,
                            float* __restrict__ out,
                            float C) {
    const int tid = threadIdx.x;
    float acc = 0.f;
    for (int i = tid; i < NROWS; i += 256) acc += partial[i];

    #pragma unroll
    for (int off = 1; off < 64; off <<= 1) acc += __shfl_xor(acc, off);

    __shared__ float sacc[4];
    const int wave = tid >> 6;
    const int lane = tid & 63;
    if (lane == 0) sacc[wave] = acc;
    __syncthreads();

    if (tid == 0) {
        float t = (sacc[0] + sacc[1]) + (sacc[2] + sacc[3]);
        out[0] = C + t / (float)NROWS;
    }
}

extern "C" void kernel_launch(void* const* d_in, const int* in_sizes, int n_in,
                              void* d_out, int out_size, void* d_ws, size_t ws_size,
                              hipStream_t stream) {
    const float* x = (const float*)d_in[0];
    const int*   y = (const int*)d_in[1];
    float* out     = (float*)d_out;
    float* partial = (float*)d_ws;   // 4096 floats, fully rewritten each call

    const double eps = 0.1;
    const double pb  = eps / (32000.0 - 1.0);
    const float  C   = (float)(eps * log(pb) + (1.0 - eps) * log(1.0 - eps));

    ls_kldiv_row_kernel<<<NROWS, 256, 0, stream>>>(x, y, partial);
    ls_kldiv_reduce_kernel<<<1, 256, 0, stream>>>(partial, out, C);
}